// Round 5
// baseline (1156.314 us; speedup 1.0000x reference)
//
#include <hip/hip_runtime.h>

// Problem constants: B=2, T=4096, D=2048, N=8 heads, K=1 kv-head, H=256
#define T_SEQ 4096
#define D_MODEL 2048
#define N_HEADS 8
#define HDIM 256

typedef unsigned int uint32;
typedef unsigned short u16;
typedef __attribute__((ext_vector_type(8))) short short8;  // 8 bf16 (4 VGPRs)
typedef __attribute__((ext_vector_type(4))) float f32x4;

__device__ __forceinline__ float bf2f(u16 v) {
  return __uint_as_float(((uint32)v) << 16);
}
__device__ __forceinline__ u16 f2bf(float f) {
  uint32 u = __float_as_uint(f);
  u += 0x7fffu + ((u >> 16) & 1u);  // round-to-nearest-even
  return (u16)(u >> 16);
}
__device__ __forceinline__ uint2 pack4(const f32x4 v) {
  uint2 r;
  r.x = (uint32)f2bf(v[0]) | ((uint32)f2bf(v[1]) << 16);
  r.y = (uint32)f2bf(v[2]) | ((uint32)f2bf(v[3]) << 16);
  return r;
}
// async global->LDS, 16B per lane; LDS dest must be lane-contiguous.
__device__ __forceinline__ void gload16(const u16* g, u16* l) {
  __builtin_amdgcn_global_load_lds(
      (const __attribute__((address_space(1))) unsigned int*)g,
      (__attribute__((address_space(3))) unsigned int*)l, 16, 0, 0);
}

// ---------------------------------------------------------------------------
// Prep 1: x (f32) -> xb (bf16), row-major [8192][2048].
// ---------------------------------------------------------------------------
__global__ __launch_bounds__(256) void convert_x(const float* __restrict__ x,
                                                 u16* __restrict__ xb) {
  const int idx = blockIdx.x * 256 + threadIdx.x;  // 4 elems each
  float4 v = *(const float4*)(x + (size_t)idx * 4);
  uint2 pk;
  pk.x = (uint32)f2bf(v.x) | ((uint32)f2bf(v.y) << 16);
  pk.y = (uint32)f2bf(v.z) | ((uint32)f2bf(v.w) << 16);
  *(uint2*)(xb + (size_t)idx * 4) = pk;
}

// ---------------------------------------------------------------------------
// Prep 2: transpose+convert weights to bf16 B^T layouts:
//   z=0: W_all[d][c] (c<2048: qw head c>>8 col c&255; else kv) -> Wt[c][d]
//   z=1: ow[k][d] (k = n*256+h)                                -> Owt[d][k]
// ---------------------------------------------------------------------------
__global__ __launch_bounds__(256) void prep_weights(
    const float* __restrict__ qw, const float* __restrict__ kvw,
    const float* __restrict__ ow, u16* __restrict__ Wt, u16* __restrict__ Owt) {
  __shared__ float Ts[64][65];
  const int t = threadIdx.x;
  const int tx = blockIdx.x, ty = blockIdx.y, z = blockIdx.z;
  const float* src;
  int srcStride;
  u16* dst;
  if (z == 0) {
    const int c0 = tx * 64;
    const float* base = (c0 < 2048)
                            ? qw + (size_t)(c0 >> 8) * D_MODEL * HDIM
                            : kvw + (size_t)((c0 - 2048) >> 8) * D_MODEL * HDIM;
    src = base + (c0 & 255);
    srcStride = HDIM;
    dst = Wt + (size_t)c0 * D_MODEL;
  } else {
    if (tx >= 32) return;
    src = ow + tx * 64;
    srcStride = D_MODEL;
    dst = Owt + (size_t)tx * 64 * D_MODEL;
  }
  const int d0 = ty * 64;
  const int r = t >> 4, c4 = (t & 15) * 4;
#pragma unroll
  for (int i = 0; i < 4; ++i) {
    float4 v = *(const float4*)(src + (size_t)(d0 + r + i * 16) * srcStride + c4);
    *(float4*)&Ts[r + i * 16][c4] = v;
  }
  __syncthreads();
#pragma unroll
  for (int i = 0; i < 4; ++i) {
    const int crow = r + i * 16;  // output row (source col)
    uint2 pk;
    pk.x = (uint32)f2bf(Ts[c4 + 0][crow]) | ((uint32)f2bf(Ts[c4 + 1][crow]) << 16);
    pk.y = (uint32)f2bf(Ts[c4 + 2][crow]) | ((uint32)f2bf(Ts[c4 + 3][crow]) << 16);
    *(uint2*)(dst + (size_t)crow * D_MODEL + d0 + c4) = pk;
  }
}

// ---------------------------------------------------------------------------
// MFMA GEMM 1: [xb 8192x2048 bf16] @ [Wt^T] -> Q/K/V.  cols: 0..2047 Q,
// 2048..2303 K, 2304..2559 V (written transposed Vt[b][h][s]).
// ---------------------------------------------------------------------------
__global__ __launch_bounds__(256) void gemm_qkv_mfma(
    const u16* __restrict__ xb, const u16* __restrict__ Wt,
    u16* __restrict__ Qb, u16* __restrict__ Kb, u16* __restrict__ Vt) {
  __shared__ u16 Asm[128][32];
  __shared__ u16 Bsm[128][32];
  const int t = threadIdx.x;
  const int w = t >> 6, l = t & 63, quad = l >> 4, lq = l & 15;
  const int wm = w & 1, wn = w >> 1;
  const int col0 = blockIdx.x * 128, row0 = blockIdx.y * 128;
  const u16* ga0 = xb + (size_t)(row0 + (t >> 2)) * D_MODEL + (t & 3) * 8;
  const u16* ga1 = ga0 + (size_t)64 * D_MODEL;
  const u16* gb0 = Wt + (size_t)(col0 + (t >> 2)) * D_MODEL + (t & 3) * 8;
  const u16* gb1 = gb0 + (size_t)64 * D_MODEL;
  u16* lA0 = &Asm[0][0] + t * 8;
  u16* lA1 = lA0 + 2048;
  u16* lB0 = &Bsm[0][0] + t * 8;
  u16* lB1 = lB0 + 2048;
  f32x4 acc[4][4];
#pragma unroll
  for (int i = 0; i < 4; ++i)
#pragma unroll
    for (int j = 0; j < 4; ++j) acc[i][j] = (f32x4){0.f, 0.f, 0.f, 0.f};
  for (int k0 = 0; k0 < D_MODEL; k0 += 32) {
    gload16(ga0 + k0, lA0);
    gload16(ga1 + k0, lA1);
    gload16(gb0 + k0, lB0);
    gload16(gb1 + k0, lB1);
    __syncthreads();
    short8 af[4], bf[4];
#pragma unroll
    for (int i = 0; i < 4; ++i)
      af[i] = *(const short8*)&Asm[wm * 64 + i * 16 + lq][quad * 8];
#pragma unroll
    for (int j = 0; j < 4; ++j)
      bf[j] = *(const short8*)&Bsm[wn * 64 + j * 16 + lq][quad * 8];
#pragma unroll
    for (int i = 0; i < 4; ++i)
#pragma unroll
      for (int j = 0; j < 4; ++j)
        acc[i][j] =
            __builtin_amdgcn_mfma_f32_16x16x32_bf16(af[i], bf[j], acc[i][j], 0, 0, 0);
    __syncthreads();
  }
  const int b = row0 >> 12, sbase = row0 & 4095;
#pragma unroll
  for (int i = 0; i < 4; ++i) {
    const int rowloc = wm * 64 + i * 16 + quad * 4;
#pragma unroll
    for (int j = 0; j < 4; ++j) {
      const int col = col0 + wn * 64 + j * 16 + lq;
      if (col < 2048) {
#pragma unroll
        for (int r = 0; r < 4; ++r)
          Qb[(size_t)(row0 + rowloc + r) * 2048 + col] = f2bf(acc[i][j][r]);
      } else if (col < 2304) {
#pragma unroll
        for (int r = 0; r < 4; ++r)
          Kb[(size_t)(row0 + rowloc + r) * HDIM + (col - 2048)] =
              f2bf(acc[i][j][r]);
      } else {
        *(uint2*)(Vt + ((size_t)b * HDIM + col - 2304) * T_SEQ + sbase + rowloc) =
            pack4(acc[i][j]);
      }
    }
  }
}

// ---------------------------------------------------------------------------
// RoPE (in-place on bf16 Q and K) + query scaling by H^-0.5.
// ---------------------------------------------------------------------------
__global__ __launch_bounds__(256) void rope_kernel(u16* __restrict__ Qb,
                                                   u16* __restrict__ Kb,
                                                   const int* __restrict__ segpos) {
  const int bt = blockIdx.x;
  const int tid = threadIdx.x;
  const float fpos = (float)segpos[bt];
  const float k_ln = 9.210340371976184f / 128.0f;  // ln(10000)/(H/2)
  for (int p = tid; p < 1024; p += 256) {
    const int n = p >> 7, i = p & 127;
    const size_t base = (size_t)bt * (N_HEADS * HDIM) + (size_t)n * HDIM;
    const float th = fpos * expf(-(float)i * k_ln);
    float s, c;
    sincosf(th, &s, &c);
    const float f1 = bf2f(Qb[base + i]);
    const float f2 = bf2f(Qb[base + i + 128]);
    Qb[base + i] = f2bf((f1 * c - f2 * s) * 0.0625f);
    Qb[base + i + 128] = f2bf((f2 * c + f1 * s) * 0.0625f);
  }
  if (tid < 128) {
    const int i = tid;
    const size_t base = (size_t)bt * HDIM;
    const float th = fpos * expf(-(float)i * k_ln);
    float s, c;
    sincosf(th, &s, &c);
    const float f1 = bf2f(Kb[base + i]);
    const float f2 = bf2f(Kb[base + i + 128]);
    Kb[base + i] = f2bf(f1 * c - f2 * s);
    Kb[base + i + 128] = f2bf(f2 * c + f1 * s);
  }
}

// ---------------------------------------------------------------------------
// MFMA flash attention (causal, MQA).
// Round 5: (a) V B-frags read DIRECTLY from global Vt[b][h][s] (16B/lane
// contiguous; L1 absorbs the 4x intra-block reuse) -- V staging + 64KB/iter
// of LDS frag reads removed; LDS 42.5 -> 22KB, 3 blocks/CU.
// (b) Ps inner stride 40 -> 44 u16: quads' dword ranges disjoint (<=2-way).
// (c) lazy O-rescale (skip 64 v_mul when no row max changed) + deferred
// l-reduction (per-lane partial sums, one shfl-reduce per tile).
// ---------------------------------------------------------------------------
__global__ __launch_bounds__(256, 3) void attn_mfma(const u16* __restrict__ Qb,
                                                    const u16* __restrict__ Kb,
                                                    const u16* __restrict__ Vt,
                                                    u16* __restrict__ Eb) {
  __shared__ u16 Ks[32][264];    // 16.9 KB  [key][h]
  __shared__ u16 Ps[4][16][44];  // 5.5 KB   per-wave P patch (stride 44!)
  const int t = threadIdx.x;
  const int w = t >> 6, l = t & 63;
  const int quad = l >> 4, lq = l & 15;
  const int bid = blockIdx.x;  // 0..31
  const int n = blockIdx.y, b = blockIdx.z;
  const u16* kgbase = Kb + (size_t)b * T_SEQ * HDIM;
  const u16* vgbase = Vt + (size_t)b * HDIM * T_SEQ;

#pragma unroll 1
  for (int ti = 0; ti < 2; ++ti) {
    const int qt = ti ? bid : 63 - bid;  // heavy tile first
    const int q0 = qt * 64;
    const int wrow0 = q0 + w * 16;

    // Q fragments: 8 chunks of K=32 head-dims, in registers for this tile.
    short8 qf[8];
    {
      const u16* qbase = Qb +
          (((size_t)b * T_SEQ + wrow0 + lq) * N_HEADS + n) * HDIM + quad * 8;
#pragma unroll
      for (int c = 0; c < 8; ++c) qf[c] = *(const short8*)(qbase + c * 32);
    }
    f32x4 O[16];
#pragma unroll
    for (int i = 0; i < 16; ++i) O[i] = (f32x4){0.f, 0.f, 0.f, 0.f};
    float m_i[4] = {-1e30f, -1e30f, -1e30f, -1e30f};
    float lsum[4] = {0.f, 0.f, 0.f, 0.f};  // per-LANE partial; reduced at end

    const int nst = 2 * qt + 2;
    for (int st = 0; st < nst; ++st) {
      const int s0 = st * 32;
      __syncthreads();  // previous iteration's K-frag reads done
      // stage K tile: 32 keys x 256 h (16 KB), coalesced 16B lanes
#pragma unroll
      for (int p = 0; p < 4; ++p) {
        const int chunk = p * 256 + t;
        const int row = chunk >> 5, col = chunk & 31;
        *(uint4*)&Ks[row][col * 8] =
            *(const uint4*)(kgbase + (size_t)(s0 + row) * HDIM + col * 8);
      }
      __syncthreads();
      if (s0 <= wrow0 + 15) {  // wave-uniform skip of fully-masked tiles
        // --- S = Q.K^T ---
        f32x4 sa0 = (f32x4){0.f, 0.f, 0.f, 0.f};
        f32x4 sa1 = (f32x4){0.f, 0.f, 0.f, 0.f};
#pragma unroll
        for (int c = 0; c < 8; ++c) {
          short8 k0 = *(const short8*)&Ks[lq][c * 32 + quad * 8];
          short8 k1 = *(const short8*)&Ks[16 + lq][c * 32 + quad * 8];
          sa0 = __builtin_amdgcn_mfma_f32_16x16x32_bf16(qf[c], k0, sa0, 0, 0, 0);
          sa1 = __builtin_amdgcn_mfma_f32_16x16x32_bf16(qf[c], k1, sa1, 0, 0, 0);
        }
        if (s0 + 31 > wrow0) {  // diagonal tiles: causal mask
#pragma unroll
          for (int r = 0; r < 4; ++r) {
            const int rw = wrow0 + quad * 4 + r;
            if (s0 + lq > rw) sa0[r] = -1e30f;
            if (s0 + 16 + lq > rw) sa1[r] = -1e30f;
          }
        }
        // --- online softmax: max reduce + P, lazy rescale ---
        float al[4];
        int chg = 0;
#pragma unroll
        for (int r = 0; r < 4; ++r) {
          float mx = fmaxf(sa0[r], sa1[r]);
          mx = fmaxf(mx, __shfl_xor(mx, 1));
          mx = fmaxf(mx, __shfl_xor(mx, 2));
          mx = fmaxf(mx, __shfl_xor(mx, 4));
          mx = fmaxf(mx, __shfl_xor(mx, 8));
          if (mx > m_i[r]) chg = 1;
          const float mnew = fmaxf(m_i[r], mx);
          al[r] = __expf(m_i[r] - mnew);
          const float p0 = __expf(sa0[r] - mnew);
          const float p1 = __expf(sa1[r] - mnew);
          lsum[r] = fmaf(lsum[r], al[r], p0 + p1);
          m_i[r] = mnew;
          Ps[w][quad * 4 + r][lq] = f2bf(p0);
          Ps[w][quad * 4 + r][16 + lq] = f2bf(p1);
        }
        if (__any(chg)) {
#pragma unroll
          for (int ntl = 0; ntl < 16; ++ntl) {
            O[ntl][0] *= al[0];
            O[ntl][1] *= al[1];
            O[ntl][2] *= al[2];
            O[ntl][3] *= al[3];
          }
        }
        __asm__ volatile("s_waitcnt lgkmcnt(0)" ::: "memory");
        short8 pf = *(const short8*)&Ps[w][lq][quad * 8];
        // --- O += P.V, V fragments straight from global (Vt is [b][h][s]) ---
        const u16* vrow = vgbase + (size_t)lq * T_SEQ + s0 + quad * 8;
#pragma unroll
        for (int ntl = 0; ntl < 16; ++ntl) {
          short8 vf = *(const short8*)(vrow + (size_t)(ntl * 16) * T_SEQ);
          O[ntl] = __builtin_amdgcn_mfma_f32_16x16x32_bf16(pf, vf, O[ntl], 0, 0, 0);
        }
      }
    }
    // epilogue: reduce per-lane l partials across the 16-lane row group,
    // normalize, store encoded bf16 for this tile
    float inv[4];
#pragma unroll
    for (int r = 0; r < 4; ++r) {
      float s = lsum[r];
      s += __shfl_xor(s, 1);
      s += __shfl_xor(s, 2);
      s += __shfl_xor(s, 4);
      s += __shfl_xor(s, 8);
      inv[r] = 1.0f / s;
    }
    u16* ebase =
        Eb + (((size_t)b * T_SEQ + wrow0 + quad * 4) * N_HEADS + n) * HDIM + lq;
#pragma unroll
    for (int ntl = 0; ntl < 16; ++ntl)
#pragma unroll
      for (int r = 0; r < 4; ++r)
        ebase[(size_t)r * (N_HEADS * HDIM) + ntl * 16] = f2bf(O[ntl][r] * inv[r]);
  }
}

// ---------------------------------------------------------------------------
// MFMA GEMM 2: out[8192x2048 f32] = Eb(bf16) @ Owt^T.
// ---------------------------------------------------------------------------
__global__ __launch_bounds__(256) void gemm_out_mfma(const u16* __restrict__ E,
                                                     const u16* __restrict__ Owt,
                                                     float* __restrict__ out) {
  __shared__ u16 Asm[128][32];
  __shared__ u16 Bsm[128][32];
  const int t = threadIdx.x;
  const int w = t >> 6, l = t & 63, quad = l >> 4, lq = l & 15;
  const int wm = w & 1, wn = w >> 1;
  const int col0 = blockIdx.x * 128, row0 = blockIdx.y * 128;
  const u16* ga0 = E + (size_t)(row0 + (t >> 2)) * D_MODEL + (t & 3) * 8;
  const u16* ga1 = ga0 + (size_t)64 * D_MODEL;
  const u16* gb0 = Owt + (size_t)(col0 + (t >> 2)) * D_MODEL + (t & 3) * 8;
  const u16* gb1 = gb0 + (size_t)64 * D_MODEL;
  u16* lA0 = &Asm[0][0] + t * 8;
  u16* lA1 = lA0 + 2048;
  u16* lB0 = &Bsm[0][0] + t * 8;
  u16* lB1 = lB0 + 2048;
  f32x4 acc[4][4];
#pragma unroll
  for (int i = 0; i < 4; ++i)
#pragma unroll
    for (int j = 0; j < 4; ++j) acc[i][j] = (f32x4){0.f, 0.f, 0.f, 0.f};
  for (int k0 = 0; k0 < D_MODEL; k0 += 32) {
    gload16(ga0 + k0, lA0);
    gload16(ga1 + k0, lA1);
    gload16(gb0 + k0, lB0);
    gload16(gb1 + k0, lB1);
    __syncthreads();
    short8 af[4], bf[4];
#pragma unroll
    for (int i = 0; i < 4; ++i)
      af[i] = *(const short8*)&Asm[wm * 64 + i * 16 + lq][quad * 8];
#pragma unroll
    for (int j = 0; j < 4; ++j)
      bf[j] = *(const short8*)&Bsm[wn * 64 + j * 16 + lq][quad * 8];
#pragma unroll
    for (int i = 0; i < 4; ++i)
#pragma unroll
      for (int j = 0; j < 4; ++j)
        acc[i][j] =
            __builtin_amdgcn_mfma_f32_16x16x32_bf16(af[i], bf[j], acc[i][j], 0, 0, 0);
    __syncthreads();
  }
#pragma unroll
  for (int i = 0; i < 4; ++i) {
    const int row = row0 + wm * 64 + i * 16 + quad * 4;
#pragma unroll
    for (int j = 0; j < 4; ++j) {
      const int col = col0 + wn * 64 + j * 16 + lq;
#pragma unroll
      for (int r = 0; r < 4; ++r)
        out[(size_t)(row + r) * D_MODEL + col] = acc[i][j][r];
    }
  }
}

// ---------------------------------------------------------------------------
extern "C" void kernel_launch(void* const* d_in, const int* in_sizes, int n_in,
                              void* d_out, int out_size, void* d_ws,
                              size_t ws_size, hipStream_t stream) {
  const float* x = (const float*)d_in[0];
  const int* segpos = (const int*)d_in[1];
  // d_in[2] = attn_mask (causal tril) — analytic, not read.
  const float* qw = (const float*)d_in[3];
  const float* kvw = (const float*)d_in[4];
  const float* ow = (const float*)d_in[5];
  float* out = (float*)d_out;

  char* ws = (char*)d_ws;
  u16* Qb = (u16*)ws;                                    // 32 MiB
  u16* Kb = (u16*)(ws + (size_t)33554432);               // 4 MiB
  u16* Vt = (u16*)(ws + (size_t)37748736);               // 4 MiB (transposed)
  u16* xb = (u16*)(ws + (size_t)41943040);               // 32 MiB (aliases Eb)
  u16* Eb = xb;  // xb dead after gemm_qkv_mfma
  u16* Wt = (u16*)(ws + (size_t)75497472);               // 10 MiB
  u16* Owt = (u16*)(ws + (size_t)85983232);              // 8 MiB  (total 90 MiB)

  hipLaunchKernelGGL(convert_x, dim3(16384), dim3(256), 0, stream, x, xb);
  hipLaunchKernelGGL(prep_weights, dim3(40, 32, 2), dim3(256), 0, stream, qw,
                     kvw, ow, Wt, Owt);
  hipLaunchKernelGGL(gemm_qkv_mfma, dim3(20, 64), dim3(256), 0, stream, xb, Wt,
                     Qb, Kb, Vt);
  hipLaunchKernelGGL(rope_kernel, dim3(8192), dim3(256), 0, stream, Qb, Kb,
                     segpos);
  hipLaunchKernelGGL(attn_mfma, dim3(32, N_HEADS, 2), dim3(256), 0, stream, Qb,
                     Kb, Vt, Eb);
  hipLaunchKernelGGL(gemm_out_mfma, dim3(16, 64), dim3(256), 0, stream, Eb, Owt,
                     out);
}

// Round 6
// 959.609 us; speedup vs baseline: 1.2050x; 1.2050x over previous
//
#include <hip/hip_runtime.h>

// Problem constants: B=2, T=4096, D=2048, N=8 heads, K=1 kv-head, H=256
#define T_SEQ 4096
#define D_MODEL 2048
#define N_HEADS 8
#define HDIM 256

typedef unsigned int uint32;
typedef unsigned short u16;
typedef __attribute__((ext_vector_type(8))) short short8;  // 8 bf16 (4 VGPRs)
typedef __attribute__((ext_vector_type(4))) float f32x4;

__device__ __forceinline__ float bf2f(u16 v) {
  return __uint_as_float(((uint32)v) << 16);
}
__device__ __forceinline__ u16 f2bf(float f) {
  uint32 u = __float_as_uint(f);
  u += 0x7fffu + ((u >> 16) & 1u);  // round-to-nearest-even
  return (u16)(u >> 16);
}
__device__ __forceinline__ uint2 pack4(const f32x4 v) {
  uint2 r;
  r.x = (uint32)f2bf(v[0]) | ((uint32)f2bf(v[1]) << 16);
  r.y = (uint32)f2bf(v[2]) | ((uint32)f2bf(v[3]) << 16);
  return r;
}
// async global->LDS, 16B per lane; LDS dest must be lane-contiguous.
__device__ __forceinline__ void gload16(const u16* g, u16* l) {
  __builtin_amdgcn_global_load_lds(
      (const __attribute__((address_space(1))) unsigned int*)g,
      (__attribute__((address_space(3))) unsigned int*)l, 16, 0, 0);
}

// ---------------------------------------------------------------------------
// Prep 1: x (f32) -> xb (bf16), row-major [8192][2048].
// ---------------------------------------------------------------------------
__global__ __launch_bounds__(256) void convert_x(const float* __restrict__ x,
                                                 u16* __restrict__ xb) {
  const int idx = blockIdx.x * 256 + threadIdx.x;  // 4 elems each
  float4 v = *(const float4*)(x + (size_t)idx * 4);
  uint2 pk;
  pk.x = (uint32)f2bf(v.x) | ((uint32)f2bf(v.y) << 16);
  pk.y = (uint32)f2bf(v.z) | ((uint32)f2bf(v.w) << 16);
  *(uint2*)(xb + (size_t)idx * 4) = pk;
}

// ---------------------------------------------------------------------------
// Prep 2: transpose+convert weights to bf16 B^T layouts:
//   z=0: W_all[d][c] (c<2048: qw head c>>8 col c&255; else kv) -> Wt[c][d]
//   z=1: ow[k][d] (k = n*256+h)                                -> Owt[d][k]
// ---------------------------------------------------------------------------
__global__ __launch_bounds__(256) void prep_weights(
    const float* __restrict__ qw, const float* __restrict__ kvw,
    const float* __restrict__ ow, u16* __restrict__ Wt, u16* __restrict__ Owt) {
  __shared__ float Ts[64][65];
  const int t = threadIdx.x;
  const int tx = blockIdx.x, ty = blockIdx.y, z = blockIdx.z;
  const float* src;
  int srcStride;
  u16* dst;
  if (z == 0) {
    const int c0 = tx * 64;
    const float* base = (c0 < 2048)
                            ? qw + (size_t)(c0 >> 8) * D_MODEL * HDIM
                            : kvw + (size_t)((c0 - 2048) >> 8) * D_MODEL * HDIM;
    src = base + (c0 & 255);
    srcStride = HDIM;
    dst = Wt + (size_t)c0 * D_MODEL;
  } else {
    if (tx >= 32) return;
    src = ow + tx * 64;
    srcStride = D_MODEL;
    dst = Owt + (size_t)tx * 64 * D_MODEL;
  }
  const int d0 = ty * 64;
  const int r = t >> 4, c4 = (t & 15) * 4;
#pragma unroll
  for (int i = 0; i < 4; ++i) {
    float4 v = *(const float4*)(src + (size_t)(d0 + r + i * 16) * srcStride + c4);
    *(float4*)&Ts[r + i * 16][c4] = v;
  }
  __syncthreads();
#pragma unroll
  for (int i = 0; i < 4; ++i) {
    const int crow = r + i * 16;  // output row (source col)
    uint2 pk;
    pk.x = (uint32)f2bf(Ts[c4 + 0][crow]) | ((uint32)f2bf(Ts[c4 + 1][crow]) << 16);
    pk.y = (uint32)f2bf(Ts[c4 + 2][crow]) | ((uint32)f2bf(Ts[c4 + 3][crow]) << 16);
    *(uint2*)(dst + (size_t)crow * D_MODEL + d0 + c4) = pk;
  }
}

// ---------------------------------------------------------------------------
// MFMA GEMM 1: [xb 8192x2048 bf16] @ [Wt^T] -> Q/K/V.  cols: 0..2047 Q,
// 2048..2303 K, 2304..2559 V (written transposed Vt[b][h][s]).
// ---------------------------------------------------------------------------
__global__ __launch_bounds__(256) void gemm_qkv_mfma(
    const u16* __restrict__ xb, const u16* __restrict__ Wt,
    u16* __restrict__ Qb, u16* __restrict__ Kb, u16* __restrict__ Vt) {
  __shared__ u16 Asm[128][32];
  __shared__ u16 Bsm[128][32];
  const int t = threadIdx.x;
  const int w = t >> 6, l = t & 63, quad = l >> 4, lq = l & 15;
  const int wm = w & 1, wn = w >> 1;
  const int col0 = blockIdx.x * 128, row0 = blockIdx.y * 128;
  const u16* ga0 = xb + (size_t)(row0 + (t >> 2)) * D_MODEL + (t & 3) * 8;
  const u16* ga1 = ga0 + (size_t)64 * D_MODEL;
  const u16* gb0 = Wt + (size_t)(col0 + (t >> 2)) * D_MODEL + (t & 3) * 8;
  const u16* gb1 = gb0 + (size_t)64 * D_MODEL;
  u16* lA0 = &Asm[0][0] + t * 8;
  u16* lA1 = lA0 + 2048;
  u16* lB0 = &Bsm[0][0] + t * 8;
  u16* lB1 = lB0 + 2048;
  f32x4 acc[4][4];
#pragma unroll
  for (int i = 0; i < 4; ++i)
#pragma unroll
    for (int j = 0; j < 4; ++j) acc[i][j] = (f32x4){0.f, 0.f, 0.f, 0.f};
  for (int k0 = 0; k0 < D_MODEL; k0 += 32) {
    gload16(ga0 + k0, lA0);
    gload16(ga1 + k0, lA1);
    gload16(gb0 + k0, lB0);
    gload16(gb1 + k0, lB1);
    __syncthreads();
    short8 af[4], bf[4];
#pragma unroll
    for (int i = 0; i < 4; ++i)
      af[i] = *(const short8*)&Asm[wm * 64 + i * 16 + lq][quad * 8];
#pragma unroll
    for (int j = 0; j < 4; ++j)
      bf[j] = *(const short8*)&Bsm[wn * 64 + j * 16 + lq][quad * 8];
#pragma unroll
    for (int i = 0; i < 4; ++i)
#pragma unroll
      for (int j = 0; j < 4; ++j)
        acc[i][j] =
            __builtin_amdgcn_mfma_f32_16x16x32_bf16(af[i], bf[j], acc[i][j], 0, 0, 0);
    __syncthreads();
  }
  const int b = row0 >> 12, sbase = row0 & 4095;
#pragma unroll
  for (int i = 0; i < 4; ++i) {
    const int rowloc = wm * 64 + i * 16 + quad * 4;
#pragma unroll
    for (int j = 0; j < 4; ++j) {
      const int col = col0 + wn * 64 + j * 16 + lq;
      if (col < 2048) {
#pragma unroll
        for (int r = 0; r < 4; ++r)
          Qb[(size_t)(row0 + rowloc + r) * 2048 + col] = f2bf(acc[i][j][r]);
      } else if (col < 2304) {
#pragma unroll
        for (int r = 0; r < 4; ++r)
          Kb[(size_t)(row0 + rowloc + r) * HDIM + (col - 2048)] =
              f2bf(acc[i][j][r]);
      } else {
        *(uint2*)(Vt + ((size_t)b * HDIM + col - 2304) * T_SEQ + sbase + rowloc) =
            pack4(acc[i][j]);
      }
    }
  }
}

// ---------------------------------------------------------------------------
// RoPE (in-place on bf16 Q and K) + query scaling by H^-0.5.
// Round 6: vectorized — 8 pairs per thread via uint4 loads/stores.
// t<128: Q (head n = t>>4, i-base (t&15)*8).  t in [128,144): K (8 pairs).
// ---------------------------------------------------------------------------
__global__ __launch_bounds__(256) void rope_kernel(u16* __restrict__ Qb,
                                                   u16* __restrict__ Kb,
                                                   const int* __restrict__ segpos) {
  const int bt = blockIdx.x;
  const int t = threadIdx.x;
  const float fpos = (float)segpos[bt];
  const float k_ln = 9.210340371976184f / 128.0f;  // ln(10000)/(H/2)
  u16* base;
  float scale;
  int ib;
  if (t < 128) {
    base = Qb + (size_t)bt * (N_HEADS * HDIM) + (size_t)(t >> 4) * HDIM;
    ib = (t & 15) * 8;
    scale = 0.0625f;
  } else if (t < 144) {
    base = Kb + (size_t)bt * HDIM;
    ib = (t - 128) * 8;
    scale = 1.0f;
  } else {
    return;
  }
  uint4 lo = *(const uint4*)(base + ib);
  uint4 hi = *(const uint4*)(base + ib + 128);
  const u16* lp = (const u16*)&lo;
  const u16* hp = (const u16*)&hi;
  u16 ro[8], rh[8];
#pragma unroll
  for (int j = 0; j < 8; ++j) {
    const float th = fpos * __expf(-(float)(ib + j) * k_ln);
    float s, c;
    __sincosf(th, &s, &c);
    const float f1 = bf2f(lp[j]);
    const float f2 = bf2f(hp[j]);
    ro[j] = f2bf((f1 * c - f2 * s) * scale);
    rh[j] = f2bf((f2 * c + f1 * s) * scale);
  }
  *(uint4*)(base + ib) = *(const uint4*)ro;
  *(uint4*)(base + ib + 128) = *(const uint4*)rh;
}

// ---------------------------------------------------------------------------
// MFMA flash attention (causal, MQA).
// Round 6 = round 4 structure (V staged in LDS, coalesced) +
//   (b) Ps inner stride 44 (quads' dword ranges disjoint, <=2-way banks)
//   (c) lazy O-rescale + deferred l-reduction (per-lane partials).
// Complementary-pair load balance: block bid does Q-tiles {63-bid, bid}.
// ---------------------------------------------------------------------------
__global__ __launch_bounds__(256, 3) void attn_mfma(const u16* __restrict__ Qb,
                                                    const u16* __restrict__ Kb,
                                                    const u16* __restrict__ Vt,
                                                    u16* __restrict__ Eb) {
  __shared__ u16 Ks[32][264];    // 16.9 KB  [key][h]
  __shared__ u16 Vs[256][40];    // 20.5 KB  [h][key]
  __shared__ u16 Ps[4][16][44];  // 5.6 KB   per-wave P patch (stride 44)
  const int t = threadIdx.x;
  const int w = t >> 6, l = t & 63;
  const int quad = l >> 4, lq = l & 15;
  const int bid = blockIdx.x;  // 0..31
  const int n = blockIdx.y, b = blockIdx.z;
  const u16* kgbase = Kb + (size_t)b * T_SEQ * HDIM;
  const u16* vgbase = Vt + (size_t)b * HDIM * T_SEQ;

#pragma unroll 1
  for (int ti = 0; ti < 2; ++ti) {
    const int qt = ti ? bid : 63 - bid;  // heavy tile first
    const int q0 = qt * 64;
    const int wrow0 = q0 + w * 16;

    // Q fragments: 8 chunks of K=32 head-dims, in registers for this tile.
    short8 qf[8];
    {
      const u16* qbase = Qb +
          (((size_t)b * T_SEQ + wrow0 + lq) * N_HEADS + n) * HDIM + quad * 8;
#pragma unroll
      for (int c = 0; c < 8; ++c) qf[c] = *(const short8*)(qbase + c * 32);
    }
    f32x4 O[16];
#pragma unroll
    for (int i = 0; i < 16; ++i) O[i] = (f32x4){0.f, 0.f, 0.f, 0.f};
    float m_i[4] = {-1e30f, -1e30f, -1e30f, -1e30f};
    float lsum[4] = {0.f, 0.f, 0.f, 0.f};  // per-LANE partial; reduced at end

    const int nst = 2 * qt + 2;
    for (int st = 0; st < nst; ++st) {
      const int s0 = st * 32;
      __syncthreads();  // previous iteration's LDS reads done
      // stage K tile: 32 keys x 256 h (16 KB), coalesced 16B lanes
#pragma unroll
      for (int p = 0; p < 4; ++p) {
        const int chunk = p * 256 + t;
        const int row = chunk >> 5, col = chunk & 31;
        *(uint4*)&Ks[row][col * 8] =
            *(const uint4*)(kgbase + (size_t)(s0 + row) * HDIM + col * 8);
      }
      // stage V tile (transposed in global): 256 h x 32 keys, coalesced
#pragma unroll
      for (int p = 0; p < 4; ++p) {
        const int chunk = p * 256 + t;
        const int row = chunk >> 2, c4 = chunk & 3;
        *(uint4*)&Vs[row][c4 * 8] =
            *(const uint4*)(vgbase + (size_t)row * T_SEQ + s0 + c4 * 8);
      }
      __syncthreads();
      if (s0 <= wrow0 + 15) {  // wave-uniform skip of fully-masked tiles
        // --- S = Q.K^T ---
        f32x4 sa0 = (f32x4){0.f, 0.f, 0.f, 0.f};
        f32x4 sa1 = (f32x4){0.f, 0.f, 0.f, 0.f};
#pragma unroll
        for (int c = 0; c < 8; ++c) {
          short8 k0 = *(const short8*)&Ks[lq][c * 32 + quad * 8];
          short8 k1 = *(const short8*)&Ks[16 + lq][c * 32 + quad * 8];
          sa0 = __builtin_amdgcn_mfma_f32_16x16x32_bf16(qf[c], k0, sa0, 0, 0, 0);
          sa1 = __builtin_amdgcn_mfma_f32_16x16x32_bf16(qf[c], k1, sa1, 0, 0, 0);
        }
        if (s0 + 31 > wrow0) {  // diagonal tiles: causal mask
#pragma unroll
          for (int r = 0; r < 4; ++r) {
            const int rw = wrow0 + quad * 4 + r;
            if (s0 + lq > rw) sa0[r] = -1e30f;
            if (s0 + 16 + lq > rw) sa1[r] = -1e30f;
          }
        }
        // --- online softmax: max reduce + P, lazy rescale ---
        float al[4];
        int chg = 0;
#pragma unroll
        for (int r = 0; r < 4; ++r) {
          float mx = fmaxf(sa0[r], sa1[r]);
          mx = fmaxf(mx, __shfl_xor(mx, 1));
          mx = fmaxf(mx, __shfl_xor(mx, 2));
          mx = fmaxf(mx, __shfl_xor(mx, 4));
          mx = fmaxf(mx, __shfl_xor(mx, 8));
          if (mx > m_i[r]) chg = 1;
          const float mnew = fmaxf(m_i[r], mx);
          al[r] = __expf(m_i[r] - mnew);
          const float p0 = __expf(sa0[r] - mnew);
          const float p1 = __expf(sa1[r] - mnew);
          lsum[r] = fmaf(lsum[r], al[r], p0 + p1);
          m_i[r] = mnew;
          Ps[w][quad * 4 + r][lq] = f2bf(p0);
          Ps[w][quad * 4 + r][16 + lq] = f2bf(p1);
        }
        if (__any(chg)) {
#pragma unroll
          for (int ntl = 0; ntl < 16; ++ntl) {
            O[ntl][0] *= al[0];
            O[ntl][1] *= al[1];
            O[ntl][2] *= al[2];
            O[ntl][3] *= al[3];
          }
        }
        __asm__ volatile("s_waitcnt lgkmcnt(0)" ::: "memory");
        short8 pf = *(const short8*)&Ps[w][lq][quad * 8];
        // --- O += P.V ---
#pragma unroll
        for (int ntl = 0; ntl < 16; ++ntl) {
          short8 vf = *(const short8*)&Vs[ntl * 16 + lq][quad * 8];
          O[ntl] = __builtin_amdgcn_mfma_f32_16x16x32_bf16(pf, vf, O[ntl], 0, 0, 0);
        }
      }
    }
    // epilogue: reduce per-lane l partials, normalize, store bf16
    float inv[4];
#pragma unroll
    for (int r = 0; r < 4; ++r) {
      float s = lsum[r];
      s += __shfl_xor(s, 1);
      s += __shfl_xor(s, 2);
      s += __shfl_xor(s, 4);
      s += __shfl_xor(s, 8);
      inv[r] = 1.0f / s;
    }
    u16* ebase =
        Eb + (((size_t)b * T_SEQ + wrow0 + quad * 4) * N_HEADS + n) * HDIM + lq;
#pragma unroll
    for (int ntl = 0; ntl < 16; ++ntl)
#pragma unroll
      for (int r = 0; r < 4; ++r)
        ebase[(size_t)r * (N_HEADS * HDIM) + ntl * 16] = f2bf(O[ntl][r] * inv[r]);
  }
}

// ---------------------------------------------------------------------------
// MFMA GEMM 2: out[8192x2048 f32] = Eb(bf16) @ Owt^T.
// ---------------------------------------------------------------------------
__global__ __launch_bounds__(256) void gemm_out_mfma(const u16* __restrict__ E,
                                                     const u16* __restrict__ Owt,
                                                     float* __restrict__ out) {
  __shared__ u16 Asm[128][32];
  __shared__ u16 Bsm[128][32];
  const int t = threadIdx.x;
  const int w = t >> 6, l = t & 63, quad = l >> 4, lq = l & 15;
  const int wm = w & 1, wn = w >> 1;
  const int col0 = blockIdx.x * 128, row0 = blockIdx.y * 128;
  const u16* ga0 = E + (size_t)(row0 + (t >> 2)) * D_MODEL + (t & 3) * 8;
  const u16* ga1 = ga0 + (size_t)64 * D_MODEL;
  const u16* gb0 = Owt + (size_t)(col0 + (t >> 2)) * D_MODEL + (t & 3) * 8;
  const u16* gb1 = gb0 + (size_t)64 * D_MODEL;
  u16* lA0 = &Asm[0][0] + t * 8;
  u16* lA1 = lA0 + 2048;
  u16* lB0 = &Bsm[0][0] + t * 8;
  u16* lB1 = lB0 + 2048;
  f32x4 acc[4][4];
#pragma unroll
  for (int i = 0; i < 4; ++i)
#pragma unroll
    for (int j = 0; j < 4; ++j) acc[i][j] = (f32x4){0.f, 0.f, 0.f, 0.f};
  for (int k0 = 0; k0 < D_MODEL; k0 += 32) {
    gload16(ga0 + k0, lA0);
    gload16(ga1 + k0, lA1);
    gload16(gb0 + k0, lB0);
    gload16(gb1 + k0, lB1);
    __syncthreads();
    short8 af[4], bf[4];
#pragma unroll
    for (int i = 0; i < 4; ++i)
      af[i] = *(const short8*)&Asm[wm * 64 + i * 16 + lq][quad * 8];
#pragma unroll
    for (int j = 0; j < 4; ++j)
      bf[j] = *(const short8*)&Bsm[wn * 64 + j * 16 + lq][quad * 8];
#pragma unroll
    for (int i = 0; i < 4; ++i)
#pragma unroll
      for (int j = 0; j < 4; ++j)
        acc[i][j] =
            __builtin_amdgcn_mfma_f32_16x16x32_bf16(af[i], bf[j], acc[i][j], 0, 0, 0);
    __syncthreads();
  }
#pragma unroll
  for (int i = 0; i < 4; ++i) {
    const int row = row0 + wm * 64 + i * 16 + quad * 4;
#pragma unroll
    for (int j = 0; j < 4; ++j) {
      const int col = col0 + wn * 64 + j * 16 + lq;
#pragma unroll
      for (int r = 0; r < 4; ++r)
        out[(size_t)(row + r) * D_MODEL + col] = acc[i][j][r];
    }
  }
}

// ---------------------------------------------------------------------------
extern "C" void kernel_launch(void* const* d_in, const int* in_sizes, int n_in,
                              void* d_out, int out_size, void* d_ws,
                              size_t ws_size, hipStream_t stream) {
  const float* x = (const float*)d_in[0];
  const int* segpos = (const int*)d_in[1];
  // d_in[2] = attn_mask (causal tril) — analytic, not read.
  const float* qw = (const float*)d_in[3];
  const float* kvw = (const float*)d_in[4];
  const float* ow = (const float*)d_in[5];
  float* out = (float*)d_out;

  char* ws = (char*)d_ws;
  u16* Qb = (u16*)ws;                                    // 32 MiB
  u16* Kb = (u16*)(ws + (size_t)33554432);               // 4 MiB
  u16* Vt = (u16*)(ws + (size_t)37748736);               // 4 MiB (transposed)
  u16* xb = (u16*)(ws + (size_t)41943040);               // 32 MiB (aliases Eb)
  u16* Eb = xb;  // xb dead after gemm_qkv_mfma
  u16* Wt = (u16*)(ws + (size_t)75497472);               // 10 MiB
  u16* Owt = (u16*)(ws + (size_t)85983232);              // 8 MiB  (total 90 MiB)

  hipLaunchKernelGGL(convert_x, dim3(16384), dim3(256), 0, stream, x, xb);
  hipLaunchKernelGGL(prep_weights, dim3(40, 32, 2), dim3(256), 0, stream, qw,
                     kvw, ow, Wt, Owt);
  hipLaunchKernelGGL(gemm_qkv_mfma, dim3(20, 64), dim3(256), 0, stream, xb, Wt,
                     Qb, Kb, Vt);
  hipLaunchKernelGGL(rope_kernel, dim3(8192), dim3(256), 0, stream, Qb, Kb,
                     segpos);
  hipLaunchKernelGGL(attn_mfma, dim3(32, N_HEADS, 2), dim3(256), 0, stream, Qb,
                     Kb, Vt, Eb);
  hipLaunchKernelGGL(gemm_out_mfma, dim3(16, 64), dim3(256), 0, stream, Eb, Owt,
                     out);
}